// Round 7
// baseline (450.685 us; speedup 1.0000x reference)
//
#include <hip/hip_runtime.h>
#include <cstddef>
#include <cstdint>

#define HEADS 4
#define OUTC  40
#define NEG   0.2f
#define EPSV  1e-16f

typedef __bf16 bf16x8 __attribute__((ext_vector_type(8)));
typedef float  floatx4 __attribute__((ext_vector_type(4)));

__device__ __forceinline__ void split_bf16(float a, unsigned& hi, unsigned& lo) {
  unsigned u = __float_as_uint(a);
  hi = u >> 16;                                   // RTZ high bf16
  float hf = __uint_as_float(u & 0xFFFF0000u);
  lo = __float_as_uint(a - hf) >> 16;             // RTZ residual bf16
}

// async global->LDS DMA, 16B per lane. lds ptr must be wave-uniform base;
// HW writes lane i at base + i*16 (m97/m104).
__device__ __forceinline__ void dma16(const void* g, void* l) {
  __builtin_amdgcn_global_load_lds(
      (const __attribute__((address_space(1))) unsigned int*)g,
      (__attribute__((address_space(3))) unsigned int*)l, 16, 0, 0);
}

// ---------------- CSR build ----------------
__global__ void hist_k(const int* __restrict__ dst, int* __restrict__ cnt, int E) {
  int e = blockIdx.x * blockDim.x + threadIdx.x;
  if (e < E) atomicAdd(&cnt[dst[e]], 1);
}

__global__ __launch_bounds__(1024) void scanA_k(const int* __restrict__ cnt,
                                                int* __restrict__ rp,
                                                int* __restrict__ bsum, int n) {
  __shared__ int sh[1024];
  int i = blockIdx.x * 1024 + threadIdx.x;
  int v = (i < n) ? cnt[i] : 0;
  sh[threadIdx.x] = v;
  __syncthreads();
  for (int d = 1; d < 1024; d <<= 1) {
    int t = (threadIdx.x >= d) ? sh[threadIdx.x - d] : 0;
    __syncthreads();
    sh[threadIdx.x] += t;
    __syncthreads();
  }
  if (i < n) rp[i] = sh[threadIdx.x] - v;  // block-local exclusive
  if (threadIdx.x == 1023) bsum[blockIdx.x] = sh[1023];
}

// adds bsum prefix to rp (folds old scanB); rp[n] = total
__global__ void scanC_k(int* __restrict__ rp, const int* __restrict__ bsum,
                        int n, int nb) {
  int i = blockIdx.x * blockDim.x + threadIdx.x;
  if (i < n) {
    int b = i >> 10;
    int off = 0;
    for (int j = 0; j < b; ++j) off += bsum[j];  // <=48 iters, L2-cached
    rp[i] += off;
  }
  if (i == 0) {
    int tot = 0;
    for (int j = 0; j < nb; ++j) tot += bsum[j];
    rp[n] = tot;
  }
}

__global__ void scatter_k(const int* __restrict__ src, const int* __restrict__ dst,
                          const int* __restrict__ rp, int* __restrict__ cur,
                          int* __restrict__ out, int E) {
  int e = blockIdx.x * blockDim.x + threadIdx.x;
  if (e < E) {
    int d = dst[e];
    int p = rp[d] + atomicAdd(&cur[d], 1);
    out[p] = src[e];
  }
}

// ---------------- weight pre-split (merged W1+W2): fp32 -> [n][K] bf16 hi/lo ----------
__global__ void convW_k(const float* __restrict__ W1, unsigned short* __restrict__ Wh1,
                        unsigned short* __restrict__ Wl1,
                        const float* __restrict__ W2, unsigned short* __restrict__ Wh2,
                        unsigned short* __restrict__ Wl2) {
  int id = blockIdx.x * 256 + threadIdx.x;
  if (id < 256 * 512) {  // W1 [512,256] -> [256][512]
    int n = id >> 9, k = id & 511;
    unsigned h, l;
    split_bf16(W1[k * 256 + n], h, l);
    Wh1[id] = (unsigned short)h;
    Wl1[id] = (unsigned short)l;
  } else {               // W2 [256,160] -> padded [256][256]
    int id2 = id - 256 * 512;
    int n = id2 >> 8, k = id2 & 255;
    int hh = n >> 6, c = n & 63;
    float a = (c < OUTC) ? W2[k * 160 + hh * OUTC + c] : 0.f;
    unsigned h, l;
    split_bf16(a, h, l);
    Wh2[id2] = (unsigned short)h;
    Wl2[id2] = (unsigned short)l;
  }
}

// ---------------- m97-style DMA GEMM: C[M,256] = A[M,K] @ B[K,256] ----------------
// 64x128 tile (R7: was 128x128 -> grid 782 = 3/CU starved overlap; now 1564 = 6/CU,
// LDS 24KB caps at 6 blocks/CU), BK=32, 2-barrier K-loop, all staging via
// global_load_lds (no staging VGPRs -> no spill; R3-R5: VGPR-staged always spills).
// A_FP32: A fp32 [M,K] staged raw, split to bf16 hi/lo at frag read.
// else:   A pre-split bf16 [M,K] hi/lo. B always pre-split bf16 [n][K].
// COMPACT: store [M,160] head-compact.
template <bool A_FP32, bool COMPACT>
__global__ __launch_bounds__(256) void gemm_dma(const void* Aptr_h, const void* Aptr_l,
                                                const unsigned short* __restrict__ Bh,
                                                const unsigned short* __restrict__ Bl,
                                                float* __restrict__ C, int M, int K) {
  __shared__ __align__(16) unsigned char lds_raw[24576];
  // A_FP32:  Af [64][32] f32 @0 (8KB)
  // !A_FP32: Ahs [64][32] bf16 @0 (4KB), Als @4096
  // both:    Bhs [128][32] bf16 @8192 (8KB), Bls @16384
  const int tid = threadIdx.x;
  const int lane = tid & 63;
  const int w = tid >> 6;
  const int wr = w >> 1, wc = w & 1;          // wave grid 2x2, each 32x64
  const int row0 = blockIdx.y * 64;
  const int col0 = blockIdx.x * 128;
  const int fr = lane & 15, fq = lane >> 4;

  floatx4 acc[2][4];
#pragma unroll
  for (int i = 0; i < 2; ++i)
#pragma unroll
    for (int j = 0; j < 4; ++j) acc[i][j] = (floatx4){0.f, 0.f, 0.f, 0.f};

  const float* Af32 = (const float*)Aptr_h;
  const unsigned short* Agh = (const unsigned short*)Aptr_h;
  const unsigned short* Agl = (const unsigned short*)Aptr_l;

  for (int k0 = 0; k0 < K; k0 += 32) {
    // ---- stage via DMA: 6 instrs/wave ----
    if (A_FP32) {
      // A 64x32 f32 = 8KB; 2 dma/wave (8 rows per dma, 128B/row)
#pragma unroll
      for (int t = 0; t < 2; ++t) {
        int arow = w * 16 + t * 8 + (lane >> 3);
        int gr = row0 + arow; gr = gr < M ? gr : M - 1;  // clamp: dup rows unused
        dma16(&Af32[(size_t)gr * K + k0 + (lane & 7) * 4],
              lds_raw + (size_t)(w * 16 + t * 8) * 128);
      }
    } else {
      // A hi/lo 64x32 bf16 = 4KB each; 1 dma/wave each (16 rows per dma, 64B/row)
      {
        int arow = w * 16 + (lane >> 2);
        int gr = row0 + arow; gr = gr < M ? gr : M - 1;
        size_t go = (size_t)gr * K + k0 + (lane & 3) * 8;
        dma16(&Agh[go], lds_raw + (size_t)(w * 16) * 64);
        dma16(&Agl[go], lds_raw + 4096 + (size_t)(w * 16) * 64);
      }
    }
    // B hi/lo 128x32 bf16 = 8KB each; 2 dma/wave each
#pragma unroll
    for (int t = 0; t < 2; ++t) {
      int nrow = w * 32 + t * 16 + (lane >> 2);
      size_t go = (size_t)(col0 + nrow) * K + k0 + (lane & 3) * 8;
      dma16(&Bh[go], lds_raw + 8192 + (size_t)(w * 32 + t * 16) * 64);
      dma16(&Bl[go], lds_raw + 16384 + (size_t)(w * 32 + t * 16) * 64);
    }
    __syncthreads();  // drains vmcnt -> tiles ready

    // ---- fragments ----
    bf16x8 ah[2], al[2], bh[4], bl[4];
#pragma unroll
    for (int i = 0; i < 2; ++i) {
      int arow = wr * 32 + i * 16 + fr;
      if (A_FP32) {
        const float* pr = (const float*)(lds_raw + (size_t)arow * 128 + fq * 32);
        float4 v0 = *(const float4*)pr;
        float4 v1 = *(const float4*)(pr + 4);
        unsigned u0 = __float_as_uint(v0.x), u1 = __float_as_uint(v0.y);
        unsigned u2 = __float_as_uint(v0.z), u3 = __float_as_uint(v0.w);
        unsigned u4 = __float_as_uint(v1.x), u5 = __float_as_uint(v1.y);
        unsigned u6 = __float_as_uint(v1.z), u7 = __float_as_uint(v1.w);
        uint4 H;
        H.x = (u0 >> 16) | (u1 & 0xFFFF0000u);
        H.y = (u2 >> 16) | (u3 & 0xFFFF0000u);
        H.z = (u4 >> 16) | (u5 & 0xFFFF0000u);
        H.w = (u6 >> 16) | (u7 & 0xFFFF0000u);
        uint4 L;
        L.x = (__float_as_uint(v0.x - __uint_as_float(u0 & 0xFFFF0000u)) >> 16) |
              (__float_as_uint(v0.y - __uint_as_float(u1 & 0xFFFF0000u)) & 0xFFFF0000u);
        L.y = (__float_as_uint(v0.z - __uint_as_float(u2 & 0xFFFF0000u)) >> 16) |
              (__float_as_uint(v0.w - __uint_as_float(u3 & 0xFFFF0000u)) & 0xFFFF0000u);
        L.z = (__float_as_uint(v1.x - __uint_as_float(u4 & 0xFFFF0000u)) >> 16) |
              (__float_as_uint(v1.y - __uint_as_float(u5 & 0xFFFF0000u)) & 0xFFFF0000u);
        L.w = (__float_as_uint(v1.z - __uint_as_float(u6 & 0xFFFF0000u)) >> 16) |
              (__float_as_uint(v1.w - __uint_as_float(u7 & 0xFFFF0000u)) & 0xFFFF0000u);
        ah[i] = *(bf16x8*)&H;
        al[i] = *(bf16x8*)&L;
      } else {
        ah[i] = *(bf16x8*)(lds_raw + (size_t)arow * 64 + fq * 16);
        al[i] = *(bf16x8*)(lds_raw + 4096 + (size_t)arow * 64 + fq * 16);
      }
    }
#pragma unroll
    for (int j = 0; j < 4; ++j) {
      int brow = wc * 64 + j * 16 + fr;
      bh[j] = *(bf16x8*)(lds_raw + 8192 + (size_t)brow * 64 + fq * 16);
      bl[j] = *(bf16x8*)(lds_raw + 16384 + (size_t)brow * 64 + fq * 16);
    }
#pragma unroll
    for (int i = 0; i < 2; ++i)
#pragma unroll
      for (int j = 0; j < 4; ++j) {
        acc[i][j] = __builtin_amdgcn_mfma_f32_16x16x32_bf16(ah[i], bh[j], acc[i][j], 0, 0, 0);
        acc[i][j] = __builtin_amdgcn_mfma_f32_16x16x32_bf16(ah[i], bl[j], acc[i][j], 0, 0, 0);
        acc[i][j] = __builtin_amdgcn_mfma_f32_16x16x32_bf16(al[i], bh[j], acc[i][j], 0, 0, 0);
      }
    __syncthreads();  // frag reads done before next iter's DMA overwrites
  }

  // epilogue: C/D layout col=lane&15, row=(lane>>4)*4+r  [m89]
#pragma unroll
  for (int i = 0; i < 2; ++i) {
    int grow_base = row0 + wr * 32 + i * 16 + fq * 4;
#pragma unroll
    for (int r = 0; r < 4; ++r) {
      int grow = grow_base + r;
      if (grow < M) {
        if (COMPACT) {
          int head = blockIdx.x * 2 + wc;
#pragma unroll
          for (int j = 0; j < 4; ++j) {
            int cc = j * 16 + fr;
            if (cc < OUTC) C[(size_t)grow * 160 + head * OUTC + cc] = acc[i][j][r];
          }
        } else {
#pragma unroll
          for (int j = 0; j < 4; ++j)
            C[(size_t)grow * 256 + col0 + wc * 64 + j * 16 + fr] = acc[i][j][r];
        }
      }
    }
  }
}

// ---------------- layer-1 agg: wave per node; emits pre-split bf16 activations ----
__global__ __launch_bounds__(256) void agg1_k(const float* __restrict__ h,
                                              const int* __restrict__ rp,
                                              const int* __restrict__ srt,
                                              const float* __restrict__ b1,
                                              unsigned short* __restrict__ outh,
                                              unsigned short* __restrict__ outl, int Nn) {
  int wv = threadIdx.x >> 6, lane = threadIdx.x & 63;
  int node = blockIdx.x * 4 + wv;
  if (node >= Nn) node = Nn - 1;
  const float4 xi = *(const float4*)&h[(size_t)node * 256 + lane * 4];
  float p = xi.x * xi.x + xi.y * xi.y + xi.z * xi.z + xi.w * xi.w;
  p += __shfl_xor(p, 1); p += __shfl_xor(p, 2); p += __shfl_xor(p, 4); p += __shfl_xor(p, 8);
  float a = p > 0.f ? p : NEG * p;      // self-loop logit
  float m = a, l = 1.f;
  float4 acc = xi;
  const int e0 = rp[node], e1 = rp[node + 1];
  for (int e = e0; e < e1; ++e) {
    int s = srt[e];
    const float4 xj = *(const float4*)&h[(size_t)s * 256 + lane * 4];
    float q = xi.x * xj.x + xi.y * xj.y + xi.z * xj.z + xi.w * xj.w;
    q += __shfl_xor(q, 1); q += __shfl_xor(q, 2); q += __shfl_xor(q, 4); q += __shfl_xor(q, 8);
    float al = q > 0.f ? q : NEG * q;
    float nm = fmaxf(m, al);
    float sc = __expf(m - nm), wt = __expf(al - nm);
    l = l * sc + wt;
    acc.x = acc.x * sc + wt * xj.x;
    acc.y = acc.y * sc + wt * xj.y;
    acc.z = acc.z * sc + wt * xj.z;
    acc.w = acc.w * sc + wt * xj.w;
    m = nm;
  }
  float inv = 1.f / (l + EPSV);
  const float4 bb = *(const float4*)&b1[lane * 4];
  float4 o;
  o.x = acc.x * inv + bb.x;
  o.y = acc.y * inv + bb.y;
  o.z = acc.z * inv + bb.z;
  o.w = acc.w * inv + bb.w;
  o.x = o.x > 0.f ? o.x : __expf(o.x) - 1.f;
  o.y = o.y > 0.f ? o.y : __expf(o.y) - 1.f;
  o.z = o.z > 0.f ? o.z : __expf(o.z) - 1.f;
  o.w = o.w > 0.f ? o.w : __expf(o.w) - 1.f;
  unsigned h0, l0, h1, l1, h2, l2, h3, l3;
  split_bf16(o.x, h0, l0);
  split_bf16(o.y, h1, l1);
  split_bf16(o.z, h2, l2);
  split_bf16(o.w, h3, l3);
  size_t base = (size_t)node * 256 + lane * 4;
  *(uint2*)&outh[base] = make_uint2(h0 | (h1 << 16), h2 | (h3 << 16));
  *(uint2*)&outl[base] = make_uint2(l0 | (l1 << 16), l2 | (l3 << 16));
}

// ---------------- layer-2 agg (compact [N,160] input) + head-mean + log_softmax ----------------
__global__ __launch_bounds__(256) void agg2_k(const float* __restrict__ h,
                                              const int* __restrict__ rp,
                                              const int* __restrict__ srt,
                                              const float* __restrict__ b2,
                                              float* __restrict__ out, int Nn) {
  __shared__ float buf[4][160];
  int wv = threadIdx.x >> 6, lane = threadIdx.x & 63;
  int node = blockIdx.x * 4 + wv;
  if (node >= Nn) node = Nn - 1;
  const int head = lane >> 4, c4 = lane & 15;
  const bool act = c4 < 10;  // 10 lanes x float4 = 40 channels per head
  float4 xi = make_float4(0.f, 0.f, 0.f, 0.f);
  if (act) xi = *(const float4*)&h[(size_t)node * 160 + head * OUTC + c4 * 4];
  float p = xi.x * xi.x + xi.y * xi.y + xi.z * xi.z + xi.w * xi.w;
  p += __shfl_xor(p, 1); p += __shfl_xor(p, 2); p += __shfl_xor(p, 4); p += __shfl_xor(p, 8);
  float a = p > 0.f ? p : NEG * p;
  float m = a, l = 1.f;
  float4 acc = xi;
  const int e0 = rp[node], e1 = rp[node + 1];
  for (int e = e0; e < e1; ++e) {
    int s = srt[e];
    float4 xj = make_float4(0.f, 0.f, 0.f, 0.f);
    if (act) xj = *(const float4*)&h[(size_t)s * 160 + head * OUTC + c4 * 4];
    float q = xi.x * xj.x + xi.y * xj.y + xi.z * xj.z + xi.w * xj.w;
    q += __shfl_xor(q, 1); q += __shfl_xor(q, 2); q += __shfl_xor(q, 4); q += __shfl_xor(q, 8);
    float al = q > 0.f ? q : NEG * q;
    float nm = fmaxf(m, al);
    float sc = __expf(m - nm), wt = __expf(al - nm);
    l = l * sc + wt;
    acc.x = acc.x * sc + wt * xj.x;
    acc.y = acc.y * sc + wt * xj.y;
    acc.z = acc.z * sc + wt * xj.z;
    acc.w = acc.w * sc + wt * xj.w;
    m = nm;
  }
  float inv = 1.f / (l + EPSV);
  if (act) {
    float4 res;
    res.x = acc.x * inv; res.y = acc.y * inv; res.z = acc.z * inv; res.w = acc.w * inv;
    *(float4*)&buf[wv][head * OUTC + c4 * 4] = res;
  }
  __syncthreads();
  const bool valid = lane < OUTC;
  float v = 0.f;
  if (valid)
    v = 0.25f * (buf[wv][lane] + buf[wv][OUTC + lane] + buf[wv][2 * OUTC + lane] +
                 buf[wv][3 * OUTC + lane]) + b2[lane];
  float t = valid ? v : -1e30f;
#pragma unroll
  for (int off = 32; off; off >>= 1) t = fmaxf(t, __shfl_xor(t, off));
  float ex = valid ? __expf(v - t) : 0.f;
  float s = ex;
#pragma unroll
  for (int off = 32; off; off >>= 1) s += __shfl_xor(s, off);
  float lse = t + __logf(s);
  if (valid) out[(size_t)node * OUTC + lane] = v - lse;
  if (blockIdx.x == 0 && threadIdx.x == 0) out[(size_t)Nn * OUTC] = 0.f;  // att_loss
}

extern "C" void kernel_launch(void* const* d_in, const int* in_sizes, int n_in,
                              void* d_out, int out_size, void* d_ws, size_t ws_size,
                              hipStream_t stream) {
  const float* x  = (const float*)d_in[0];
  const int*   ei = (const int*)d_in[1];
  const float* W1 = (const float*)d_in[2];
  const float* b1 = (const float*)d_in[3];
  const float* W2 = (const float*)d_in[4];
  const float* b2 = (const float*)d_in[5];
  float* out = (float*)d_out;

  const int Nn = in_sizes[0] / 512;  // 50000
  const int E  = in_sizes[1] / 2;    // 400000
  const int* esrc = ei;
  const int* edst = ei + E;
  const int NB = (Nn + 1023) / 1024;

  // workspace layout
  char* ws = (char*)d_ws;
  const size_t szH = (size_t)Nn * 256 * sizeof(float);  // 51.2 MB
  float* h1 = (float*)(ws);           // GEMM1 out [N,256] f32; reused as h2 [N,160] f32
  size_t off = szH;
  unsigned short* g1h = (unsigned short*)(ws + off); off += (size_t)Nn * 256 * 2;  // 25.6MB
  unsigned short* g1l = (unsigned short*)(ws + off); off += (size_t)Nn * 256 * 2;
  int* rp = (int*)(ws + off);   off += ((size_t)(Nn + 1) * 4 + 15) & ~(size_t)15;
  int* cnt = (int*)(ws + off);  off += ((size_t)Nn * 4 + 15) & ~(size_t)15;
  int* srt = (int*)(ws + off);  off += ((size_t)E * 4 + 15) & ~(size_t)15;
  int* bsum = (int*)(ws + off); off += 1024;
  unsigned short* Wh1 = (unsigned short*)(ws + off); off += (size_t)256 * 512 * 2;
  unsigned short* Wl1 = (unsigned short*)(ws + off); off += (size_t)256 * 512 * 2;
  unsigned short* Wh2 = (unsigned short*)(ws + off); off += (size_t)256 * 256 * 2;
  unsigned short* Wl2 = (unsigned short*)(ws + off); off += (size_t)256 * 256 * 2;
  float* h2 = h1;

  // CSR by destination
  hipMemsetAsync(cnt, 0, (size_t)Nn * sizeof(int), stream);
  hist_k<<<(E + 255) / 256, 256, 0, stream>>>(edst, cnt, E);
  scanA_k<<<NB, 1024, 0, stream>>>(cnt, rp, bsum, Nn);
  scanC_k<<<(Nn + 255) / 256, 256, 0, stream>>>(rp, bsum, Nn, NB);
  hipMemsetAsync(cnt, 0, (size_t)Nn * sizeof(int), stream);
  scatter_k<<<(E + 255) / 256, 256, 0, stream>>>(esrc, edst, rp, cnt, srt, E);

  // weight pre-split (merged)
  convW_k<<<768, 256, 0, stream>>>(W1, Wh1, Wl1, W2, Wh2, Wl2);

  // layer 1: A = x fp32 (read-time split), B = Wh1/Wl1
  gemm_dma<true, false>
      <<<dim3(2, (Nn + 63) / 64), 256, 0, stream>>>(x, nullptr, Wh1, Wl1, h1, Nn, 512);
  agg1_k<<<(Nn + 3) / 4, 256, 0, stream>>>(h1, rp, srt, b1, g1h, g1l, Nn);

  // layer 2: A = g1 pre-split bf16, compact [N,160] output
  gemm_dma<false, true>
      <<<dim3(2, (Nn + 63) / 64), 256, 0, stream>>>(g1h, g1l, Wh2, Wl2, h2, Nn, 256);
  agg2_k<<<(Nn + 3) / 4, 256, 0, stream>>>(h2, rp, srt, b2, out, Nn);
}

// Round 8
// 426.057 us; speedup vs baseline: 1.0578x; 1.0578x over previous
//
#include <hip/hip_runtime.h>
#include <cstddef>
#include <cstdint>

#define HEADS 4
#define OUTC  40
#define NEG   0.2f
#define EPSV  1e-16f

typedef __bf16 bf16x8 __attribute__((ext_vector_type(8)));
typedef float  floatx4 __attribute__((ext_vector_type(4)));

__device__ __forceinline__ void split_bf16(float a, unsigned& hi, unsigned& lo) {
  unsigned u = __float_as_uint(a);
  hi = u >> 16;                                   // RTZ high bf16
  float hf = __uint_as_float(u & 0xFFFF0000u);
  lo = __float_as_uint(a - hf) >> 16;             // RTZ residual bf16
}

// async global->LDS DMA, 16B per lane. lds ptr must be wave-uniform base;
// HW writes lane i at base + i*16 (m97/m104).
__device__ __forceinline__ void dma16(const void* g, void* l) {
  __builtin_amdgcn_global_load_lds(
      (const __attribute__((address_space(1))) unsigned int*)g,
      (__attribute__((address_space(3))) unsigned int*)l, 16, 0, 0);
}

// ---------------- CSR build ----------------
__global__ void hist_k(const int* __restrict__ dst, int* __restrict__ cnt, int E) {
  int e = blockIdx.x * blockDim.x + threadIdx.x;
  if (e < E) atomicAdd(&cnt[dst[e]], 1);
}

__global__ __launch_bounds__(1024) void scanA_k(const int* __restrict__ cnt,
                                                int* __restrict__ rp,
                                                int* __restrict__ bsum, int n) {
  __shared__ int sh[1024];
  int i = blockIdx.x * 1024 + threadIdx.x;
  int v = (i < n) ? cnt[i] : 0;
  sh[threadIdx.x] = v;
  __syncthreads();
  for (int d = 1; d < 1024; d <<= 1) {
    int t = (threadIdx.x >= d) ? sh[threadIdx.x - d] : 0;
    __syncthreads();
    sh[threadIdx.x] += t;
    __syncthreads();
  }
  if (i < n) rp[i] = sh[threadIdx.x] - v;  // block-local exclusive
  if (threadIdx.x == 1023) bsum[blockIdx.x] = sh[1023];
}

// adds bsum prefix to rp (folds old scanB); rp[n] = total
__global__ void scanC_k(int* __restrict__ rp, const int* __restrict__ bsum,
                        int n, int nb) {
  int i = blockIdx.x * blockDim.x + threadIdx.x;
  if (i < n) {
    int b = i >> 10;
    int off = 0;
    for (int j = 0; j < b; ++j) off += bsum[j];  // <=48 iters, L2-cached
    rp[i] += off;
  }
  if (i == 0) {
    int tot = 0;
    for (int j = 0; j < nb; ++j) tot += bsum[j];
    rp[n] = tot;
  }
}

__global__ void scatter_k(const int* __restrict__ src, const int* __restrict__ dst,
                          const int* __restrict__ rp, int* __restrict__ cur,
                          int* __restrict__ out, int E) {
  int e = blockIdx.x * blockDim.x + threadIdx.x;
  if (e < E) {
    int d = dst[e];
    int p = rp[d] + atomicAdd(&cur[d], 1);
    out[p] = src[e];
  }
}

// ---------------- weight pre-split (merged W1+W2): fp32 -> [n][K] bf16 hi/lo ----------
__global__ void convW_k(const float* __restrict__ W1, unsigned short* __restrict__ Wh1,
                        unsigned short* __restrict__ Wl1,
                        const float* __restrict__ W2, unsigned short* __restrict__ Wh2,
                        unsigned short* __restrict__ Wl2) {
  int id = blockIdx.x * 256 + threadIdx.x;
  if (id < 256 * 512) {  // W1 [512,256] -> [256][512]
    int n = id >> 9, k = id & 511;
    unsigned h, l;
    split_bf16(W1[k * 256 + n], h, l);
    Wh1[id] = (unsigned short)h;
    Wl1[id] = (unsigned short)l;
  } else {               // W2 [256,160] -> padded [256][256]
    int id2 = id - 256 * 512;
    int n = id2 >> 8, k = id2 & 255;
    int hh = n >> 6, c = n & 63;
    float a = (c < OUTC) ? W2[k * 160 + hh * OUTC + c] : 0.f;
    unsigned h, l;
    split_bf16(a, h, l);
    Wh2[id2] = (unsigned short)h;
    Wl2[id2] = (unsigned short)l;
  }
}

// ---------------- double-buffered DMA GEMM: C[M,256] = A[M,K] @ B[K,256] ----------
// 128x128 tile, BK=32, LDS 2x32KB. K-loop restructured (R8): issue tile k+1's 8
// DMAs, then s_waitcnt vmcnt(8) (waits tile k only, k+1 stays in flight) + RAW
// s_barrier (inline asm, memory clobber) -- avoids __syncthreads' vmcnt(0)
// drain that exposed ~2x900cyc HBM latency per iter (R6/R7 postmortem; m135
// vmcnt semantics, m139 raw-barrier precedent). Second raw barrier protects
// the buffer overwritten next iter (ds_reads already consumed by MFMA).
// Staging stays DMA-only: VGPR-staged pipelines always spill (R3-R5).
template <bool A_FP32, bool COMPACT>
__global__ __launch_bounds__(256) void gemm_dma(const void* Aptr_h, const void* Aptr_l,
                                                const unsigned short* __restrict__ Bh,
                                                const unsigned short* __restrict__ Bl,
                                                float* __restrict__ C, int M, int K) {
  // per-buffer layout (base = (k&1)*32768):
  //  A_FP32:  Af [128][32] f32 @0 (16KB)
  //  !A_FP32: Ahs [128][32] bf16 @0 (8KB), Als @8192
  //  both:    Bhs [128][32] bf16 @16384 (8KB), Bls @24576
  __shared__ __align__(16) unsigned char lds[65536];
  const int tid = threadIdx.x;
  const int lane = tid & 63;
  const int w = tid >> 6;
  const int wr = w >> 1, wc = w & 1;
  const int row0 = blockIdx.y * 128;
  const int col0 = blockIdx.x * 128;
  const int fr = lane & 15, fq = lane >> 4;

  floatx4 acc[4][4];
#pragma unroll
  for (int i = 0; i < 4; ++i)
#pragma unroll
    for (int j = 0; j < 4; ++j) acc[i][j] = (floatx4){0.f, 0.f, 0.f, 0.f};

  const float* Af32 = (const float*)Aptr_h;
  const unsigned short* Agh = (const unsigned short*)Aptr_h;
  const unsigned short* Agl = (const unsigned short*)Aptr_l;

  // 8 DMA instrs per wave per tile (both variants)
#define DMA_TILE(K0, BASE)                                                          \
  do {                                                                              \
    if (A_FP32) {                                                                   \
      _Pragma("unroll") for (int t = 0; t < 4; ++t) {                               \
        int arow = w * 32 + t * 8 + (lane >> 3);                                    \
        int gr = row0 + arow; gr = gr < M ? gr : M - 1;                             \
        dma16(&Af32[(size_t)gr * K + (K0) + (lane & 7) * 4],                        \
              lds + (BASE) + (size_t)(w * 32 + t * 8) * 128);                       \
      }                                                                             \
    } else {                                                                        \
      _Pragma("unroll") for (int t = 0; t < 2; ++t) {                               \
        int arow = w * 32 + t * 16 + (lane >> 2);                                   \
        int gr = row0 + arow; gr = gr < M ? gr : M - 1;                             \
        size_t go = (size_t)gr * K + (K0) + (lane & 3) * 8;                         \
        dma16(&Agh[go], lds + (BASE) + (size_t)(w * 32 + t * 16) * 64);             \
        dma16(&Agl[go], lds + (BASE) + 8192 + (size_t)(w * 32 + t * 16) * 64);      \
      }                                                                             \
    }                                                                               \
    _Pragma("unroll") for (int t = 0; t < 2; ++t) {                                 \
      int nrow = w * 32 + t * 16 + (lane >> 2);                                     \
      size_t go = (size_t)(col0 + nrow) * K + (K0) + (lane & 3) * 8;                \
      dma16(&Bh[go], lds + (BASE) + 16384 + (size_t)(w * 32 + t * 16) * 64);        \
      dma16(&Bl[go], lds + (BASE) + 24576 + (size_t)(w * 32 + t * 16) * 64);        \
    }                                                                               \
  } while (0)

  const int nk = K >> 5;
  DMA_TILE(0, 0);
  for (int k = 0; k < nk; ++k) {
    const int cur = (k & 1) << 15;
    if (k + 1 < nk) {
      DMA_TILE((k + 1) << 5, ((k + 1) & 1) << 15);
      asm volatile("s_waitcnt vmcnt(8)" ::: "memory");  // tile k done; k+1 in flight
    } else {
      asm volatile("s_waitcnt vmcnt(0)" ::: "memory");
    }
    asm volatile("s_barrier" ::: "memory");

    bf16x8 ah[4], al[4], bh[4], bl[4];
#pragma unroll
    for (int i = 0; i < 4; ++i) {
      int arow = wr * 64 + i * 16 + fr;
      if (A_FP32) {
        const float* pr = (const float*)(lds + cur + (size_t)arow * 128 + fq * 32);
        float4 v0 = *(const float4*)pr;
        float4 v1 = *(const float4*)(pr + 4);
        unsigned u0 = __float_as_uint(v0.x), u1 = __float_as_uint(v0.y);
        unsigned u2 = __float_as_uint(v0.z), u3 = __float_as_uint(v0.w);
        unsigned u4 = __float_as_uint(v1.x), u5 = __float_as_uint(v1.y);
        unsigned u6 = __float_as_uint(v1.z), u7 = __float_as_uint(v1.w);
        uint4 H;
        H.x = (u0 >> 16) | (u1 & 0xFFFF0000u);
        H.y = (u2 >> 16) | (u3 & 0xFFFF0000u);
        H.z = (u4 >> 16) | (u5 & 0xFFFF0000u);
        H.w = (u6 >> 16) | (u7 & 0xFFFF0000u);
        uint4 L;
        L.x = (__float_as_uint(v0.x - __uint_as_float(u0 & 0xFFFF0000u)) >> 16) |
              (__float_as_uint(v0.y - __uint_as_float(u1 & 0xFFFF0000u)) & 0xFFFF0000u);
        L.y = (__float_as_uint(v0.z - __uint_as_float(u2 & 0xFFFF0000u)) >> 16) |
              (__float_as_uint(v0.w - __uint_as_float(u3 & 0xFFFF0000u)) & 0xFFFF0000u);
        L.z = (__float_as_uint(v1.x - __uint_as_float(u4 & 0xFFFF0000u)) >> 16) |
              (__float_as_uint(v1.y - __uint_as_float(u5 & 0xFFFF0000u)) & 0xFFFF0000u);
        L.w = (__float_as_uint(v1.z - __uint_as_float(u6 & 0xFFFF0000u)) >> 16) |
              (__float_as_uint(v1.w - __uint_as_float(u7 & 0xFFFF0000u)) & 0xFFFF0000u);
        ah[i] = *(bf16x8*)&H;
        al[i] = *(bf16x8*)&L;
      } else {
        ah[i] = *(bf16x8*)(lds + cur + (size_t)arow * 64 + fq * 16);
        al[i] = *(bf16x8*)(lds + cur + 8192 + (size_t)arow * 64 + fq * 16);
      }
      int brow = wc * 64 + i * 16 + fr;
      bh[i] = *(bf16x8*)(lds + cur + 16384 + (size_t)brow * 64 + fq * 16);
      bl[i] = *(bf16x8*)(lds + cur + 24576 + (size_t)brow * 64 + fq * 16);
    }
#pragma unroll
    for (int i = 0; i < 4; ++i)
#pragma unroll
      for (int j = 0; j < 4; ++j) {
        acc[i][j] = __builtin_amdgcn_mfma_f32_16x16x32_bf16(ah[i], bh[j], acc[i][j], 0, 0, 0);
        acc[i][j] = __builtin_amdgcn_mfma_f32_16x16x32_bf16(ah[i], bl[j], acc[i][j], 0, 0, 0);
        acc[i][j] = __builtin_amdgcn_mfma_f32_16x16x32_bf16(al[i], bh[j], acc[i][j], 0, 0, 0);
      }
    asm volatile("s_barrier" ::: "memory");  // buf[k&1] free for overwrite at k+1
  }
#undef DMA_TILE

  // epilogue: C/D layout col=lane&15, row=(lane>>4)*4+r  [m89]
#pragma unroll
  for (int i = 0; i < 4; ++i) {
    int grow_base = row0 + wr * 64 + i * 16 + fq * 4;
#pragma unroll
    for (int r = 0; r < 4; ++r) {
      int grow = grow_base + r;
      if (grow < M) {
        if (COMPACT) {
          int head = blockIdx.x * 2 + wc;
#pragma unroll
          for (int j = 0; j < 4; ++j) {
            int cc = j * 16 + fr;
            if (cc < OUTC) C[(size_t)grow * 160 + head * OUTC + cc] = acc[i][j][r];
          }
        } else {
#pragma unroll
          for (int j = 0; j < 4; ++j)
            C[(size_t)grow * 256 + col0 + wc * 64 + j * 16 + fr] = acc[i][j][r];
        }
      }
    }
  }
}

// ---------------- layer-1 agg: wave per node; emits pre-split bf16 activations ----
__global__ __launch_bounds__(256) void agg1_k(const float* __restrict__ h,
                                              const int* __restrict__ rp,
                                              const int* __restrict__ srt,
                                              const float* __restrict__ b1,
                                              unsigned short* __restrict__ outh,
                                              unsigned short* __restrict__ outl, int Nn) {
  int wv = threadIdx.x >> 6, lane = threadIdx.x & 63;
  int node = blockIdx.x * 4 + wv;
  if (node >= Nn) node = Nn - 1;
  const float4 xi = *(const float4*)&h[(size_t)node * 256 + lane * 4];
  float p = xi.x * xi.x + xi.y * xi.y + xi.z * xi.z + xi.w * xi.w;
  p += __shfl_xor(p, 1); p += __shfl_xor(p, 2); p += __shfl_xor(p, 4); p += __shfl_xor(p, 8);
  float a = p > 0.f ? p : NEG * p;      // self-loop logit
  float m = a, l = 1.f;
  float4 acc = xi;
  const int e0 = rp[node], e1 = rp[node + 1];
  for (int e = e0; e < e1; ++e) {
    int s = srt[e];
    const float4 xj = *(const float4*)&h[(size_t)s * 256 + lane * 4];
    float q = xi.x * xj.x + xi.y * xj.y + xi.z * xj.z + xi.w * xj.w;
    q += __shfl_xor(q, 1); q += __shfl_xor(q, 2); q += __shfl_xor(q, 4); q += __shfl_xor(q, 8);
    float al = q > 0.f ? q : NEG * q;
    float nm = fmaxf(m, al);
    float sc = __expf(m - nm), wt = __expf(al - nm);
    l = l * sc + wt;
    acc.x = acc.x * sc + wt * xj.x;
    acc.y = acc.y * sc + wt * xj.y;
    acc.z = acc.z * sc + wt * xj.z;
    acc.w = acc.w * sc + wt * xj.w;
    m = nm;
  }
  float inv = 1.f / (l + EPSV);
  const float4 bb = *(const float4*)&b1[lane * 4];
  float4 o;
  o.x = acc.x * inv + bb.x;
  o.y = acc.y * inv + bb.y;
  o.z = acc.z * inv + bb.z;
  o.w = acc.w * inv + bb.w;
  o.x = o.x > 0.f ? o.x : __expf(o.x) - 1.f;
  o.y = o.y > 0.f ? o.y : __expf(o.y) - 1.f;
  o.z = o.z > 0.f ? o.z : __expf(o.z) - 1.f;
  o.w = o.w > 0.f ? o.w : __expf(o.w) - 1.f;
  unsigned h0, l0, h1, l1, h2, l2, h3, l3;
  split_bf16(o.x, h0, l0);
  split_bf16(o.y, h1, l1);
  split_bf16(o.z, h2, l2);
  split_bf16(o.w, h3, l3);
  size_t base = (size_t)node * 256 + lane * 4;
  *(uint2*)&outh[base] = make_uint2(h0 | (h1 << 16), h2 | (h3 << 16));
  *(uint2*)&outl[base] = make_uint2(l0 | (l1 << 16), l2 | (l3 << 16));
}

// ---------------- layer-2 agg (compact [N,160] input) + head-mean + log_softmax ----------------
__global__ __launch_bounds__(256) void agg2_k(const float* __restrict__ h,
                                              const int* __restrict__ rp,
                                              const int* __restrict__ srt,
                                              const float* __restrict__ b2,
                                              float* __restrict__ out, int Nn) {
  __shared__ float buf[4][160];
  int wv = threadIdx.x >> 6, lane = threadIdx.x & 63;
  int node = blockIdx.x * 4 + wv;
  if (node >= Nn) node = Nn - 1;
  const int head = lane >> 4, c4 = lane & 15;
  const bool act = c4 < 10;  // 10 lanes x float4 = 40 channels per head
  float4 xi = make_float4(0.f, 0.f, 0.f, 0.f);
  if (act) xi = *(const float4*)&h[(size_t)node * 160 + head * OUTC + c4 * 4];
  float p = xi.x * xi.x + xi.y * xi.y + xi.z * xi.z + xi.w * xi.w;
  p += __shfl_xor(p, 1); p += __shfl_xor(p, 2); p += __shfl_xor(p, 4); p += __shfl_xor(p, 8);
  float a = p > 0.f ? p : NEG * p;
  float m = a, l = 1.f;
  float4 acc = xi;
  const int e0 = rp[node], e1 = rp[node + 1];
  for (int e = e0; e < e1; ++e) {
    int s = srt[e];
    float4 xj = make_float4(0.f, 0.f, 0.f, 0.f);
    if (act) xj = *(const float4*)&h[(size_t)s * 160 + head * OUTC + c4 * 4];
    float q = xi.x * xj.x + xi.y * xj.y + xi.z * xj.z + xi.w * xj.w;
    q += __shfl_xor(q, 1); q += __shfl_xor(q, 2); q += __shfl_xor(q, 4); q += __shfl_xor(q, 8);
    float al = q > 0.f ? q : NEG * q;
    float nm = fmaxf(m, al);
    float sc = __expf(m - nm), wt = __expf(al - nm);
    l = l * sc + wt;
    acc.x = acc.x * sc + wt * xj.x;
    acc.y = acc.y * sc + wt * xj.y;
    acc.z = acc.z * sc + wt * xj.z;
    acc.w = acc.w * sc + wt * xj.w;
    m = nm;
  }
  float inv = 1.f / (l + EPSV);
  if (act) {
    float4 res;
    res.x = acc.x * inv; res.y = acc.y * inv; res.z = acc.z * inv; res.w = acc.w * inv;
    *(float4*)&buf[wv][head * OUTC + c4 * 4] = res;
  }
  __syncthreads();
  const bool valid = lane < OUTC;
  float v = 0.f;
  if (valid)
    v = 0.25f * (buf[wv][lane] + buf[wv][OUTC + lane] + buf[wv][2 * OUTC + lane] +
                 buf[wv][3 * OUTC + lane]) + b2[lane];
  float t = valid ? v : -1e30f;
#pragma unroll
  for (int off = 32; off; off >>= 1) t = fmaxf(t, __shfl_xor(t, off));
  float ex = valid ? __expf(v - t) : 0.f;
  float s = ex;
#pragma unroll
  for (int off = 32; off; off >>= 1) s += __shfl_xor(s, off);
  float lse = t + __logf(s);
  if (valid) out[(size_t)node * OUTC + lane] = v - lse;
  if (blockIdx.x == 0 && threadIdx.x == 0) out[(size_t)Nn * OUTC] = 0.f;  // att_loss
}

extern "C" void kernel_launch(void* const* d_in, const int* in_sizes, int n_in,
                              void* d_out, int out_size, void* d_ws, size_t ws_size,
                              hipStream_t stream) {
  const float* x  = (const float*)d_in[0];
  const int*   ei = (const int*)d_in[1];
  const float* W1 = (const float*)d_in[2];
  const float* b1 = (const float*)d_in[3];
  const float* W2 = (const float*)d_in[4];
  const float* b2 = (const float*)d_in[5];
  float* out = (float*)d_out;

  const int Nn = in_sizes[0] / 512;  // 50000
  const int E  = in_sizes[1] / 2;    // 400000
  const int* esrc = ei;
  const int* edst = ei + E;
  const int NB = (Nn + 1023) / 1024;

  // workspace layout
  char* ws = (char*)d_ws;
  const size_t szH = (size_t)Nn * 256 * sizeof(float);  // 51.2 MB
  float* h1 = (float*)(ws);           // GEMM1 out [N,256] f32; reused as h2 [N,160] f32
  size_t off = szH;
  unsigned short* g1h = (unsigned short*)(ws + off); off += (size_t)Nn * 256 * 2;  // 25.6MB
  unsigned short* g1l = (unsigned short*)(ws + off); off += (size_t)Nn * 256 * 2;
  int* rp = (int*)(ws + off);   off += ((size_t)(Nn + 1) * 4 + 15) & ~(size_t)15;
  int* cnt = (int*)(ws + off);  off += ((size_t)Nn * 4 + 15) & ~(size_t)15;
  int* srt = (int*)(ws + off);  off += ((size_t)E * 4 + 15) & ~(size_t)15;
  int* bsum = (int*)(ws + off); off += 1024;
  unsigned short* Wh1 = (unsigned short*)(ws + off); off += (size_t)256 * 512 * 2;
  unsigned short* Wl1 = (unsigned short*)(ws + off); off += (size_t)256 * 512 * 2;
  unsigned short* Wh2 = (unsigned short*)(ws + off); off += (size_t)256 * 256 * 2;
  unsigned short* Wl2 = (unsigned short*)(ws + off); off += (size_t)256 * 256 * 2;
  float* h2 = h1;

  // CSR by destination
  hipMemsetAsync(cnt, 0, (size_t)Nn * sizeof(int), stream);
  hist_k<<<(E + 255) / 256, 256, 0, stream>>>(edst, cnt, E);
  scanA_k<<<NB, 1024, 0, stream>>>(cnt, rp, bsum, Nn);
  scanC_k<<<(Nn + 255) / 256, 256, 0, stream>>>(rp, bsum, Nn, NB);
  hipMemsetAsync(cnt, 0, (size_t)Nn * sizeof(int), stream);
  scatter_k<<<(E + 255) / 256, 256, 0, stream>>>(esrc, edst, rp, cnt, srt, E);

  // weight pre-split (merged)
  convW_k<<<768, 256, 0, stream>>>(W1, Wh1, Wl1, W2, Wh2, Wl2);

  // layer 1: A = x fp32 (read-time split), B = Wh1/Wl1
  gemm_dma<true, false>
      <<<dim3(2, (Nn + 127) / 128), 256, 0, stream>>>(x, nullptr, Wh1, Wl1, h1, Nn, 512);
  agg1_k<<<(Nn + 3) / 4, 256, 0, stream>>>(h1, rp, srt, b1, g1h, g1l, Nn);

  // layer 2: A = g1 pre-split bf16, compact [N,160] output
  gemm_dma<false, true>
      <<<dim3(2, (Nn + 127) / 128), 256, 0, stream>>>(g1h, g1l, Wh2, Wl2, h2, Nn, 256);
  agg2_k<<<(Nn + 3) / 4, 256, 0, stream>>>(h2, rp, srt, b2, out, Nn);
}